// Round 11
// baseline (99.626 us; speedup 1.0000x reference)
//
#include <hip/hip_runtime.h>

typedef short bf16x8 __attribute__((ext_vector_type(8)));
typedef float f32x4 __attribute__((ext_vector_type(4)));
typedef float f32x16 __attribute__((ext_vector_type(16)));

__device__ __forceinline__ unsigned short f2bf(float f) {
  union { float f; unsigned u; } c; c.f = f;
  unsigned u = c.u;
  u += 0x7FFFu + ((u >> 16) & 1u);   // RNE
  return (unsigned short)(u >> 16);
}
__device__ __forceinline__ float bf2f(unsigned short h) {
  union { unsigned u; float f; } c; c.u = ((unsigned)h) << 16;
  return c.f;
}
// truncation split: hi = trunc-to-bf16(v), lo = RNE(v - hi)
__device__ __forceinline__ void split2(float v, unsigned short& hi, unsigned short& lo) {
  union { float f; unsigned u; } c; c.f = v;
  unsigned uh = c.u & 0xFFFF0000u;
  hi = (unsigned short)(uh >> 16);
  union { unsigned u; float f; } d; d.u = uh;
  lo = f2bf(v - d.f);
}
__device__ __forceinline__ void gload16(const void* g, void* l) {
  __builtin_amdgcn_global_load_lds((const __attribute__((address_space(1))) void*)g,
                                   (__attribute__((address_space(3))) void*)l, 16, 0, 0);
}
__device__ __forceinline__ float sigm(float x) { return 1.0f / (1.0f + __expf(-x)); }
__device__ __forceinline__ float tanha(float x) { return 1.0f - 2.0f / (1.0f + __expf(2.0f * x)); }

// Abuf 32x32x16-fragment layout (ushort index) for (row 0..8191, col 0..1279):
// 1 KiB frag = (mb, cc, rowblk, k4); within: lane = hi*32 + (row&31), e = col&7
__device__ __forceinline__ size_t fragIdxA(int row, int col) {
  int mb = row >> 7, rb = (row >> 5) & 3, l5 = row & 31;
  int cc = col >> 6, k4 = (col >> 4) & 3, hi = (col >> 3) & 1, e = col & 7;
  return ((size_t)(mb * 20 + cc) * 16 + rb * 4 + k4) * 512 + (hi * 32 + l5) * 8 + e;
}

// ---------------- merged setup kernel ----------------
// [0, 262144): Wt[n][k] = W[k][n]                    (256x1024 bf16)
// [262144, 458752): Bg[g][n][k]                      (4x192x256 bf16)
// [458752, 2621440): Btp frag-ordered                (176 blocks x 24 frags x 512)
__global__ __launch_bounds__(256) void s123(
    const float* __restrict__ W,
    const float* __restrict__ U, const float* __restrict__ UU,
    const float* __restrict__ UUU, const float* __restrict__ UUUU,
    const float* __restrict__ W1, const float* __restrict__ W2, const float* __restrict__ W3,
    const float* __restrict__ A1, const float* __restrict__ A2, const float* __restrict__ A3,
    const float* __restrict__ B1, const float* __restrict__ B2, const float* __restrict__ B3,
    const float* __restrict__ C1, const float* __restrict__ C2, const float* __restrict__ C3,
    const float* __restrict__ D1, const float* __restrict__ D2, const float* __restrict__ D3,
    unsigned short* __restrict__ Wt, unsigned short* __restrict__ Bg,
    unsigned short* __restrict__ Btp) {
  int gidx = blockIdx.x * 256 + threadIdx.x;
  if (gidx < 262144) {
    int idx = gidx;
    int n = idx >> 10, k = idx & 1023;
    Wt[idx] = f2bf(W[k * 256 + n]);
  } else if (gidx < 458752) {
    int idx = gidx - 262144;
    int g = idx / 49152;
    int rem = idx - g * 49152;
    int n = rem >> 8, k = rem & 255;
    int jj = 0, rr = n;
#pragma unroll
    for (int s = 0; s < 3; ++s) {
      int w = (((g - jj) & 3) < 2) ? 64 : 32;
      if (rr >= w) { rr -= w; ++jj; }
    }
    int v = (g - jj) & 3;
    int rv = (v < 2) ? 64 : 32;
    const float* M = (v == 0) ? U : (v == 1) ? UU : (v == 2) ? UUU : UUUU;
    Bg[idx] = f2bf(M[(jj * 256 + k) * rv + rr]);
  } else {
    int idx = gidx - 458752;                 // linear ushort index into frag-ordered Btp
    int blk = idx / 12288;                   // (j*11+kt)*4 + cb
    int w   = idx - blk * 12288;
    int frag = w >> 9, fl = (w >> 3) & 63, e = w & 7;
    int cb = blk & 3, jk = blk >> 2;
    int kt = jk % 11, j = jk / 11;
    int q = frag >> 3, colblk = (frag >> 2) & 1, k4 = frag & 3;
    int c  = cb * 64 + colblk * 32 + (fl & 31);
    int k2 = k4 * 16 + (fl >> 5) * 8 + e;
    float val;
    if (kt < 8) {
      int kk = (kt * 64 + k2) & 255;
      const float* Wp = (q == 0) ? W1 : (q == 1) ? W2 : W3;
      val = Wp[kk * 1024 + j * 256 + c];
    } else {
      int kT = (kt - 8) * 64 + k2;
      int v, r, rv;
      if (kT < 64)       { v = 0; r = kT;       rv = 64; }
      else if (kT < 128) { v = 1; r = kT - 64;  rv = 64; }
      else if (kT < 160) { v = 2; r = kT - 128; rv = 32; }
      else               { v = 3; r = kT - 160; rv = 32; }
      const float* M;
      if (v == 0)      M = (q == 0) ? A1 : (q == 1) ? A2 : A3;
      else if (v == 1) M = (q == 0) ? B1 : (q == 1) ? B2 : B3;
      else if (v == 2) M = (q == 0) ? C1 : (q == 1) ? C2 : C3;
      else             M = (q == 0) ? D1 : (q == 1) ? D2 : D3;
      val = M[(j * rv + r) * 256 + c];
    }
    Btp[idx] = f2bf(val);
  }
}

// ---------------- G1: xw = x @ W, hi/lo 2-pass, BM=32 BN=256 (x read ONCE)
// grid (256): mb only. LDS: Ahi 2x4K @0, Alo 2x4K @8192, B 2x32K @16384 (80 KiB)
__global__ __launch_bounds__(256) void g1_xw(const float* __restrict__ x,
                                             const unsigned short* __restrict__ Wt,
                                             unsigned short* __restrict__ Abuf) {
  __shared__ char lds[81920];
  const int tid = threadIdx.x, lane = tid & 63, wid = tid >> 6;
  const int mb = blockIdx.x;
  const int wm = wid >> 1, wn = wid & 1;   // wave: rows 16*wm, cols 128*wn
  f32x4 acc[8] = {};
  float4 xr[2];
  const int r0 = tid >> 4, f4c = tid & 15;
  const float* xbase = x + (size_t)(mb * 32) * 1024 + f4c * 4;

  auto loadX = [&](int kt) {
#pragma unroll
    for (int q = 0; q < 2; ++q)
      xr[q] = *(const float4*)(xbase + (size_t)(q * 16 + r0) * 1024 + kt * 64);
  };
  auto writeA = [&](int buf) {
#pragma unroll
    for (int q = 0; q < 2; ++q) {
      int row = q * 16 + r0;
      float4 v = xr[q];
      unsigned short h0, h1, h2, h3, l0, l1, l2, l3;
      split2(v.x, h0, l0); split2(v.y, h1, l1);
      split2(v.z, h2, l2); split2(v.w, h3, l3);
      int ba = row * 128 + ((f4c * 8) ^ ((row & 7) << 4));
      *(uint2*)(lds + buf * 4096 + ba) =
          make_uint2(((unsigned)h1 << 16) | h0, ((unsigned)h3 << 16) | h2);
      *(uint2*)(lds + 8192 + buf * 4096 + ba) =
          make_uint2(((unsigned)l1 << 16) | l0, ((unsigned)l3 << 16) | l2);
    }
  };
  auto stageB = [&](int kt, int buf) {
#pragma unroll
    for (int it = 0; it < 8; ++it) {
      int nloc = it * 32 + wid * 8 + (lane >> 3);
      const char* src = (const char*)Wt + (size_t)nloc * 2048 + kt * 128
                        + (((lane & 7) * 16) ^ ((nloc & 7) << 4));
      gload16(src, lds + 16384 + buf * 32768 + (it * 32 + wid * 8) * 128);
    }
  };

  loadX(0); stageB(0, 0); writeA(0);
  __syncthreads();
  for (int kt = 0; kt < 16; ++kt) {
    int buf = kt & 1;
    if (kt < 15) {
      loadX(kt + 1); stageB(kt + 1, buf ^ 1);
      asm volatile("s_waitcnt vmcnt(10)" ::: "memory");
    } else {
      asm volatile("s_waitcnt vmcnt(0)" ::: "memory");
    }
    __builtin_amdgcn_s_barrier();
    __builtin_amdgcn_sched_barrier(0);
    const char* hA = lds + buf * 4096;
    const char* lA = lds + 8192 + buf * 4096;
    const char* bB = lds + 16384 + buf * 32768;
#pragma unroll
    for (int ks = 0; ks < 2; ++ks) {
      int mloc = wm * 16 + (lane & 15);
      int ka = (ks * 64 + (lane >> 4) * 16) ^ ((mloc & 7) << 4);
      bf16x8 ah = *(const bf16x8*)(hA + mloc * 128 + ka);
      bf16x8 al = *(const bf16x8*)(lA + mloc * 128 + ka);
#pragma unroll
      for (int nf = 0; nf < 8; ++nf) {
        int nloc = wn * 128 + nf * 16 + (lane & 15);
        int kb = (ks * 64 + (lane >> 4) * 16) ^ ((nloc & 7) << 4);
        bf16x8 b = *(const bf16x8*)(bB + nloc * 128 + kb);
        acc[nf] = __builtin_amdgcn_mfma_f32_16x16x32_bf16(ah, b, acc[nf], 0, 0, 0);
        acc[nf] = __builtin_amdgcn_mfma_f32_16x16x32_bf16(al, b, acc[nf], 0, 0, 0);
      }
    }
    if (kt < 15) writeA(buf ^ 1);
    __builtin_amdgcn_sched_barrier(0);
    asm volatile("s_waitcnt lgkmcnt(0)" ::: "memory");
    __builtin_amdgcn_s_barrier();
  }
#pragma unroll
  for (int nf = 0; nf < 8; ++nf)
#pragma unroll
    for (int r = 0; r < 4; ++r) {
      int row = mb * 32 + wm * 16 + (lane >> 4) * 4 + r;
      int col = wn * 128 + nf * 16 + (lane & 15);
      float val = acc[nf][r];
      unsigned short hi, lo;
      split2(val, hi, lo);
      Abuf[fragIdxA(row, col)] = hi;
      Abuf[fragIdxA(row, col + 256)] = lo;
    }
}

// ---------------- G2: zero-skip T = h_g @ Bg, BM=64, N=192, K=256, 2-phase
__global__ __launch_bounds__(256) void g2_t(const float* __restrict__ h,
                                            const unsigned short* __restrict__ Bg,
                                            unsigned short* __restrict__ Abuf) {
  __shared__ char lds[65536];
  const int tid = threadIdx.x, lane = tid & 63, wid = tid >> 6;
  const int mb = blockIdx.x, g = blockIdx.y;
  const int wm = wid >> 1, wn = wid & 1;
  f32x4 acc[2][6] = {};
  float4 hr[4];
  const int r0 = tid >> 4, f4c = tid & 15;
  const float* hbase = h + (size_t)(mb * 64) * 1024 + g * 256 + f4c * 4;

  auto loadH = [&](int kt) {
#pragma unroll
    for (int q = 0; q < 4; ++q)
      hr[q] = *(const float4*)(hbase + (size_t)(q * 16 + r0) * 1024 + kt * 64);
  };
  auto writeA = [&](int buf) {
#pragma unroll
    for (int q = 0; q < 4; ++q) {
      int row = q * 16 + r0;
      float4 v = hr[q];
      int ba = row * 128 + ((f4c * 8) ^ ((row & 7) << 4));
      *(uint2*)(lds + buf * 8192 + ba) =
          make_uint2(((unsigned)f2bf(v.y) << 16) | f2bf(v.x),
                     ((unsigned)f2bf(v.w) << 16) | f2bf(v.z));
    }
  };
  auto stageB = [&](int kt, int buf) {
#pragma unroll
    for (int it = 0; it < 6; ++it) {
      int nloc = it * 32 + wid * 8 + (lane >> 3);
      const char* src = (const char*)Bg + (size_t)(g * 192 + nloc) * 512 + kt * 128
                        + (((lane & 7) * 16) ^ ((nloc & 7) << 4));
      gload16(src, lds + 16384 + buf * 24576 + (it * 32 + wid * 8) * 128);
    }
  };

  loadH(0); stageB(0, 0); writeA(0);
  __syncthreads();
#pragma unroll
  for (int kt = 0; kt < 4; ++kt) {
    int buf = kt & 1;
    if (kt < 3) { loadH(kt + 1); stageB(kt + 1, buf ^ 1); }
    const char* cA = lds + buf * 8192;
    const char* cB = lds + 16384 + buf * 24576;
#pragma unroll
    for (int ks = 0; ks < 2; ++ks) {
      bf16x8 a[2], b[6];
#pragma unroll
      for (int mf = 0; mf < 2; ++mf) {
        int mloc = wm * 32 + mf * 16 + (lane & 15);
        int ka = (ks * 64 + (lane >> 4) * 16) ^ ((mloc & 7) << 4);
        a[mf] = *(const bf16x8*)(cA + mloc * 128 + ka);
      }
#pragma unroll
      for (int nf = 0; nf < 6; ++nf) {
        int nloc = wn * 96 + nf * 16 + (lane & 15);
        int kb = (ks * 64 + (lane >> 4) * 16) ^ ((nloc & 7) << 4);
        b[nf] = *(const bf16x8*)(cB + nloc * 128 + kb);
      }
#pragma unroll
      for (int mf = 0; mf < 2; ++mf)
#pragma unroll
        for (int nf = 0; nf < 6; ++nf)
          acc[mf][nf] = __builtin_amdgcn_mfma_f32_16x16x32_bf16(a[mf], b[nf], acc[mf][nf], 0, 0, 0);
    }
    if (kt < 3) writeA(buf ^ 1);
    __syncthreads();
  }
#pragma unroll
  for (int mf = 0; mf < 2; ++mf)
#pragma unroll
    for (int nf = 0; nf < 6; ++nf) {
      int n = wn * 96 + nf * 16 + (lane & 15);
      int jj = 0, rr = n;
#pragma unroll
      for (int s = 0; s < 3; ++s) {
        int w = (((g - jj) & 3) < 2) ? 64 : 32;
        if (rr >= w) { rr -= w; ++jj; }
      }
      int v = (g - jj) & 3;
      int offv = (v < 2) ? (v << 6) : (64 + (v << 5));
      int col = 512 + jj * 192 + offv + rr;
#pragma unroll
      for (int r = 0; r < 4; ++r) {
        int row = mb * 64 + wm * 32 + mf * 16 + (lane >> 4) * 4 + r;
        Abuf[fragIdxA(row, col)] = f2bf(acc[mf][nf][r]);
      }
    }
}

// ---------------- G3: fused GEMM + GRU epilogue, 32x32x16, XCD-local block remap
// grid (1024): xcd = flat&7 owns mb in [xcd*8, xcd*8+8) -> per-XCD L2 holds its A slice
// Block: BM=128, 64 cols of group j, 4 waves (2M x 2N)
// LDS: A 2x16KB @0, B 2x24KB @32768 (80 KiB); counted vmcnt(10)
__global__ __launch_bounds__(256) void g3_main(const unsigned short* __restrict__ Abuf,
                                               const unsigned short* __restrict__ Btp,
                                               const float* __restrict__ h,
                                               const float* __restrict__ bias_r,
                                               const float* __restrict__ bias_g,
                                               const float* __restrict__ bias_u,
                                               float* __restrict__ out) {
  __shared__ char lds[81920];
  const int tid = threadIdx.x, lane = tid & 63, wid = tid >> 6;
  // XCD-aware remap: same-XCD blocks share an 8-mb A working set (2.6 MB < 4 MB L2)
  const int flat = blockIdx.x;
  const int xcd = flat & 7, idx = flat >> 3;
  const int mb = xcd * 8 + (idx & 7);
  const int cj = idx >> 3;
  const int cb = cj & 3, j = cj >> 2;
  const int wm = wid >> 1, wn = wid & 1;
  f32x16 acc[2][4] = {};   // [mblk][plane]

  const char* AbufB = (const char*)Abuf;
  const char* BtpB  = (const char*)Btp;

  auto stage = [&](int kt, int buf) {
    int cc = (kt < 8) ? kt : (8 + j * 3 + (kt - 8));
    const char* asrc = AbufB + (size_t)(mb * 20 + cc) * 16384 + tid * 16;
    const char* bsrc = BtpB + (size_t)(((j * 11 + kt) * 4 + cb)) * 24576 + tid * 16;
#pragma unroll
    for (int it = 0; it < 4; ++it)
      gload16(asrc + it * 4096, lds + buf * 16384 + it * 4096 + wid * 1024);
#pragma unroll
    for (int it = 0; it < 6; ++it)
      gload16(bsrc + it * 4096, lds + 32768 + buf * 24576 + it * 4096 + wid * 1024);
  };

  stage(0, 0);
#pragma unroll
  for (int kt = 0; kt < 11; ++kt) {
    const int buf = kt & 1;
    if (kt < 10) {
      stage(kt + 1, buf ^ 1);
      asm volatile("s_waitcnt vmcnt(10)" ::: "memory");
    } else {
      asm volatile("s_waitcnt vmcnt(0)" ::: "memory");
    }
    __builtin_amdgcn_s_barrier();
    __builtin_amdgcn_sched_barrier(0);
    __builtin_amdgcn_s_setprio(1);
    const char* aB = lds + buf * 16384 + wm * 8192 + lane * 16;
    const char* bB = lds + 32768 + buf * 24576 + wn * 4096 + lane * 16;
#pragma unroll
    for (int k4 = 0; k4 < 4; ++k4) {
      bf16x8 a0 = *(const bf16x8*)(aB + k4 * 1024);
      bf16x8 a1 = *(const bf16x8*)(aB + 4096 + k4 * 1024);
#pragma unroll
      for (int q = 0; q < 3; ++q) {
        const int p = (kt < 8) ? q : ((q == 2) ? 3 : q);
        bf16x8 b = *(const bf16x8*)(bB + q * 8192 + k4 * 1024);
        acc[0][p] = __builtin_amdgcn_mfma_f32_32x32x16_bf16(a0, b, acc[0][p], 0, 0, 0);
        acc[1][p] = __builtin_amdgcn_mfma_f32_32x32x16_bf16(a1, b, acc[1][p], 0, 0, 0);
      }
    }
    __builtin_amdgcn_s_setprio(0);
    __builtin_amdgcn_sched_barrier(0);
    __builtin_amdgcn_s_barrier();
  }
  // fused GRU epilogue; 32x32 C/D: col = lane&31, row = (r&3) + 8*(r>>2) + 4*(lane>>5)
  int cg = j * 256 + cb * 64 + wn * 32 + (lane & 31);
  float br = bias_r[cg], bg = bias_g[cg], bu = bias_u[cg];
#pragma unroll
  for (int mblk = 0; mblk < 2; ++mblk)
#pragma unroll
    for (int r = 0; r < 16; ++r) {
      int row = mb * 128 + wm * 64 + mblk * 32 + (r & 3) + 8 * (r >> 2) + 4 * (lane >> 5);
      float p0 = acc[mblk][0][r], p1 = acc[mblk][1][r];
      float p2 = acc[mblk][2][r], p3 = acc[mblk][3][r];
      float rr = sigm(p0 + br);
      float zz = sigm(p1 + bg);
      float ct = tanha(p2 + rr * p3 + bu);
      float hv = h[(size_t)row * 1024 + cg];
      out[(size_t)row * 1024 + cg] = zz * hv + (1.0f - zz) * ct;
    }
}

extern "C" void kernel_launch(void* const* d_in, const int* in_sizes, int n_in,
                              void* d_out, int out_size, void* d_ws, size_t ws_size,
                              hipStream_t stream) {
  const float* x   = (const float*)d_in[0];
  const float* h   = (const float*)d_in[1];
  const float* W   = (const float*)d_in[2];
  const float* W1  = (const float*)d_in[3];
  const float* W2  = (const float*)d_in[4];
  const float* W3  = (const float*)d_in[5];
  const float* U   = (const float*)d_in[6];
  const float* U1  = (const float*)d_in[7];
  const float* U2  = (const float*)d_in[8];
  const float* U3  = (const float*)d_in[9];
  const float* UU   = (const float*)d_in[10];
  const float* UU1  = (const float*)d_in[11];
  const float* UU2  = (const float*)d_in[12];
  const float* UU3  = (const float*)d_in[13];
  const float* UUU   = (const float*)d_in[14];
  const float* UUU1  = (const float*)d_in[15];
  const float* UUU2  = (const float*)d_in[16];
  const float* UUU3  = (const float*)d_in[17];
  const float* UUUU   = (const float*)d_in[18];
  const float* UUUU1  = (const float*)d_in[19];
  const float* UUUU2  = (const float*)d_in[20];
  const float* UUUU3  = (const float*)d_in[21];
  const float* bias_r = (const float*)d_in[22];
  const float* bias_g = (const float*)d_in[23];
  const float* bias_u = (const float*)d_in[24];

  char* ws = (char*)d_ws;
  unsigned short* Abuf = (unsigned short*)(ws);              // 8192x1280 bf16, frag-ordered
  unsigned short* Wt   = (unsigned short*)(ws + 20971520);   // 256x1024 bf16
  unsigned short* Bg   = (unsigned short*)(ws + 21495808);   // 4x192x256 bf16
  unsigned short* Btp  = (unsigned short*)(ws + 21889024);   // 176x24 frag-ordered bf16
  float* out = (float*)d_out;

  s123<<<10240, 256, 0, stream>>>(W, U, UU, UUU, UUUU,
                                  W1, W2, W3, U1, U2, U3, UU1, UU2, UU3,
                                  UUU1, UUU2, UUU3, UUUU1, UUUU2, UUUU3,
                                  Wt, Bg, Btp);
  g1_xw<<<256, 256, 0, stream>>>(x, Wt, Abuf);
  g2_t<<<dim3(128, 4), 256, 0, stream>>>(h, Bg, Abuf);
  g3_main<<<1024, 256, 0, stream>>>(Abuf, Btp, h, bias_r, bias_g, bias_u, out);
}

// Round 12
// 93.990 us; speedup vs baseline: 1.0600x; 1.0600x over previous
//
#include <hip/hip_runtime.h>

typedef short bf16x8 __attribute__((ext_vector_type(8)));
typedef float f32x4 __attribute__((ext_vector_type(4)));
typedef float f32x16 __attribute__((ext_vector_type(16)));

__device__ __forceinline__ unsigned short f2bf(float f) {
  union { float f; unsigned u; } c; c.f = f;
  unsigned u = c.u;
  u += 0x7FFFu + ((u >> 16) & 1u);   // RNE
  return (unsigned short)(u >> 16);
}
__device__ __forceinline__ float bf2f(unsigned short h) {
  union { unsigned u; float f; } c; c.u = ((unsigned)h) << 16;
  return c.f;
}
// truncation split: hi = trunc-to-bf16(v), lo = RNE(v - hi)
__device__ __forceinline__ void split2(float v, unsigned short& hi, unsigned short& lo) {
  union { float f; unsigned u; } c; c.f = v;
  unsigned uh = c.u & 0xFFFF0000u;
  hi = (unsigned short)(uh >> 16);
  union { unsigned u; float f; } d; d.u = uh;
  lo = f2bf(v - d.f);
}
__device__ __forceinline__ void gload16(const void* g, void* l) {
  __builtin_amdgcn_global_load_lds((const __attribute__((address_space(1))) void*)g,
                                   (__attribute__((address_space(3))) void*)l, 16, 0, 0);
}
__device__ __forceinline__ float sigm(float x) { return 1.0f / (1.0f + __expf(-x)); }
__device__ __forceinline__ float tanha(float x) { return 1.0f - 2.0f / (1.0f + __expf(2.0f * x)); }

// Abuf 32x32x16-fragment layout (ushort index) for (row 0..8191, col 0..1279):
// 1 KiB frag = (mb, cc, rowblk, k4); within: lane = hi*32 + (row&31), e = col&7
__device__ __forceinline__ size_t fragIdxA(int row, int col) {
  int mb = row >> 7, rb = (row >> 5) & 3, l5 = row & 31;
  int cc = col >> 6, k4 = (col >> 4) & 3, hi = (col >> 3) & 1, e = col & 7;
  return ((size_t)(mb * 20 + cc) * 16 + rb * 4 + k4) * 512 + (hi * 32 + l5) * 8 + e;
}

// ---------------- merged setup kernel ----------------
// [0, 262144): Wt[n][k] = W[k][n]                    (256x1024 bf16)
// [262144, 458752): Bg[g][n][k]                      (4x192x256 bf16)
// [458752, 2621440): Btp frag-ordered                (176 blocks x 24 frags x 512)
__global__ __launch_bounds__(256) void s123(
    const float* __restrict__ W,
    const float* __restrict__ U, const float* __restrict__ UU,
    const float* __restrict__ UUU, const float* __restrict__ UUUU,
    const float* __restrict__ W1, const float* __restrict__ W2, const float* __restrict__ W3,
    const float* __restrict__ A1, const float* __restrict__ A2, const float* __restrict__ A3,
    const float* __restrict__ B1, const float* __restrict__ B2, const float* __restrict__ B3,
    const float* __restrict__ C1, const float* __restrict__ C2, const float* __restrict__ C3,
    const float* __restrict__ D1, const float* __restrict__ D2, const float* __restrict__ D3,
    unsigned short* __restrict__ Wt, unsigned short* __restrict__ Bg,
    unsigned short* __restrict__ Btp) {
  int gidx = blockIdx.x * 256 + threadIdx.x;
  if (gidx < 262144) {
    int idx = gidx;
    int n = idx >> 10, k = idx & 1023;
    Wt[idx] = f2bf(W[k * 256 + n]);
  } else if (gidx < 458752) {
    int idx = gidx - 262144;
    int g = idx / 49152;
    int rem = idx - g * 49152;
    int n = rem >> 8, k = rem & 255;
    int jj = 0, rr = n;
#pragma unroll
    for (int s = 0; s < 3; ++s) {
      int w = (((g - jj) & 3) < 2) ? 64 : 32;
      if (rr >= w) { rr -= w; ++jj; }
    }
    int v = (g - jj) & 3;
    int rv = (v < 2) ? 64 : 32;
    const float* M = (v == 0) ? U : (v == 1) ? UU : (v == 2) ? UUU : UUUU;
    Bg[idx] = f2bf(M[(jj * 256 + k) * rv + rr]);
  } else {
    int idx = gidx - 458752;                 // linear ushort index into frag-ordered Btp
    int blk = idx / 12288;                   // (j*11+kt)*4 + cb
    int w   = idx - blk * 12288;
    int frag = w >> 9, fl = (w >> 3) & 63, e = w & 7;
    int cb = blk & 3, jk = blk >> 2;
    int kt = jk % 11, j = jk / 11;
    int q = frag >> 3, colblk = (frag >> 2) & 1, k4 = frag & 3;
    int c  = cb * 64 + colblk * 32 + (fl & 31);
    int k2 = k4 * 16 + (fl >> 5) * 8 + e;
    float val;
    if (kt < 8) {
      int kk = (kt * 64 + k2) & 255;
      const float* Wp = (q == 0) ? W1 : (q == 1) ? W2 : W3;
      val = Wp[kk * 1024 + j * 256 + c];
    } else {
      int kT = (kt - 8) * 64 + k2;
      int v, r, rv;
      if (kT < 64)       { v = 0; r = kT;       rv = 64; }
      else if (kT < 128) { v = 1; r = kT - 64;  rv = 64; }
      else if (kT < 160) { v = 2; r = kT - 128; rv = 32; }
      else               { v = 3; r = kT - 160; rv = 32; }
      const float* M;
      if (v == 0)      M = (q == 0) ? A1 : (q == 1) ? A2 : A3;
      else if (v == 1) M = (q == 0) ? B1 : (q == 1) ? B2 : B3;
      else if (v == 2) M = (q == 0) ? C1 : (q == 1) ? C2 : C3;
      else             M = (q == 0) ? D1 : (q == 1) ? D2 : D3;
      val = M[(j * rv + r) * 256 + c];
    }
    Btp[idx] = f2bf(val);
  }
}

// ---------------- G1 body: xw = x @ W, hi/lo 2-pass, BM=32 BN=128 (R10-proven)
__device__ __forceinline__ void g1_body(const float* __restrict__ x,
                                        const unsigned short* __restrict__ Wt,
                                        unsigned short* __restrict__ Abuf,
                                        char* lds, int mb, int nb, int tid) {
  const int lane = tid & 63, wid = tid >> 6;
  const int wm = 0, wn = wid;
  f32x4 acc[2][2] = {};
  float4 xr[2];
  const int r0 = tid >> 4, f4c = tid & 15;
  const float* xbase = x + (size_t)(mb * 32) * 1024 + f4c * 4;
  (void)wm;

  auto loadX = [&](int kt) {
#pragma unroll
    for (int q = 0; q < 2; ++q)
      xr[q] = *(const float4*)(xbase + (size_t)(q * 16 + r0) * 1024 + kt * 64);
  };
  auto writeA = [&](int buf) {
#pragma unroll
    for (int q = 0; q < 2; ++q) {
      int row = q * 16 + r0;
      float4 v = xr[q];
      unsigned short h0, h1, h2, h3, l0, l1, l2, l3;
      split2(v.x, h0, l0); split2(v.y, h1, l1);
      split2(v.z, h2, l2); split2(v.w, h3, l3);
      int ba = row * 128 + ((f4c * 8) ^ ((row & 7) << 4));
      *(uint2*)(lds + buf * 4096 + ba) =
          make_uint2(((unsigned)h1 << 16) | h0, ((unsigned)h3 << 16) | h2);
      *(uint2*)(lds + 8192 + buf * 4096 + ba) =
          make_uint2(((unsigned)l1 << 16) | l0, ((unsigned)l3 << 16) | l2);
    }
  };
  auto stageB = [&](int kt, int buf) {
#pragma unroll
    for (int it = 0; it < 4; ++it) {
      int nloc = it * 32 + wid * 8 + (lane >> 3);
      const char* src = (const char*)Wt + (size_t)(nb * 128 + nloc) * 2048 + kt * 128
                        + (((lane & 7) * 16) ^ ((nloc & 7) << 4));
      gload16(src, lds + 16384 + buf * 16384 + (it * 32 + wid * 8) * 128);
    }
  };

  loadX(0); stageB(0, 0); writeA(0);
  __syncthreads();
#pragma unroll 2
  for (int kt = 0; kt < 16; ++kt) {
    int buf = kt & 1;
    if (kt < 15) {
      loadX(kt + 1); stageB(kt + 1, buf ^ 1);
      asm volatile("s_waitcnt vmcnt(6)" ::: "memory");
    } else {
      asm volatile("s_waitcnt vmcnt(0)" ::: "memory");
    }
    __builtin_amdgcn_s_barrier();
    __builtin_amdgcn_sched_barrier(0);
    const char* hA = lds + buf * 4096;
    const char* lA = lds + 8192 + buf * 4096;
    const char* bB = lds + 16384 + buf * 16384;
#pragma unroll
    for (int ks = 0; ks < 2; ++ks) {
      bf16x8 ah[2], al[2], b[2];
#pragma unroll
      for (int mf = 0; mf < 2; ++mf) {
        int mloc = mf * 16 + (lane & 15);
        int ka = (ks * 64 + (lane >> 4) * 16) ^ ((mloc & 7) << 4);
        ah[mf] = *(const bf16x8*)(hA + mloc * 128 + ka);
        al[mf] = *(const bf16x8*)(lA + mloc * 128 + ka);
      }
#pragma unroll
      for (int nf = 0; nf < 2; ++nf) {
        int nloc = wn * 32 + nf * 16 + (lane & 15);
        int kb = (ks * 64 + (lane >> 4) * 16) ^ ((nloc & 7) << 4);
        b[nf] = *(const bf16x8*)(bB + nloc * 128 + kb);
      }
#pragma unroll
      for (int mf = 0; mf < 2; ++mf)
#pragma unroll
        for (int nf = 0; nf < 2; ++nf) {
          acc[mf][nf] = __builtin_amdgcn_mfma_f32_16x16x32_bf16(ah[mf], b[nf], acc[mf][nf], 0, 0, 0);
          acc[mf][nf] = __builtin_amdgcn_mfma_f32_16x16x32_bf16(al[mf], b[nf], acc[mf][nf], 0, 0, 0);
        }
    }
    if (kt < 15) writeA(buf ^ 1);
    __builtin_amdgcn_sched_barrier(0);
    asm volatile("s_waitcnt lgkmcnt(0)" ::: "memory");
    __builtin_amdgcn_s_barrier();
  }
#pragma unroll
  for (int mf = 0; mf < 2; ++mf)
#pragma unroll
    for (int nf = 0; nf < 2; ++nf)
#pragma unroll
      for (int r = 0; r < 4; ++r) {
        int row = mb * 32 + mf * 16 + (lane >> 4) * 4 + r;
        int col = nb * 128 + wn * 32 + nf * 16 + (lane & 15);
        float val = acc[mf][nf][r];
        unsigned short hi, lo;
        split2(val, hi, lo);
        Abuf[fragIdxA(row, col)] = hi;
        Abuf[fragIdxA(row, col + 256)] = lo;
      }
}

// ---------------- G2 body: zero-skip T = h_g @ Bg, BM=64, N=192, K=256 (R10-proven)
__device__ __forceinline__ void g2_body(const float* __restrict__ h,
                                        const unsigned short* __restrict__ Bg,
                                        unsigned short* __restrict__ Abuf,
                                        char* lds, int mb, int g, int tid) {
  const int lane = tid & 63, wid = tid >> 6;
  const int wm = wid >> 1, wn = wid & 1;
  f32x4 acc[2][6] = {};
  float4 hr[4];
  const int r0 = tid >> 4, f4c = tid & 15;
  const float* hbase = h + (size_t)(mb * 64) * 1024 + g * 256 + f4c * 4;

  auto loadH = [&](int kt) {
#pragma unroll
    for (int q = 0; q < 4; ++q)
      hr[q] = *(const float4*)(hbase + (size_t)(q * 16 + r0) * 1024 + kt * 64);
  };
  auto writeA = [&](int buf) {
#pragma unroll
    for (int q = 0; q < 4; ++q) {
      int row = q * 16 + r0;
      float4 v = hr[q];
      int ba = row * 128 + ((f4c * 8) ^ ((row & 7) << 4));
      *(uint2*)(lds + buf * 8192 + ba) =
          make_uint2(((unsigned)f2bf(v.y) << 16) | f2bf(v.x),
                     ((unsigned)f2bf(v.w) << 16) | f2bf(v.z));
    }
  };
  auto stageB = [&](int kt, int buf) {
#pragma unroll
    for (int it = 0; it < 6; ++it) {
      int nloc = it * 32 + wid * 8 + (lane >> 3);
      const char* src = (const char*)Bg + (size_t)(g * 192 + nloc) * 512 + kt * 128
                        + (((lane & 7) * 16) ^ ((nloc & 7) << 4));
      gload16(src, lds + 16384 + buf * 24576 + (it * 32 + wid * 8) * 128);
    }
  };

  loadH(0); stageB(0, 0); writeA(0);
  __syncthreads();
#pragma unroll
  for (int kt = 0; kt < 4; ++kt) {
    int buf = kt & 1;
    if (kt < 3) { loadH(kt + 1); stageB(kt + 1, buf ^ 1); }
    const char* cA = lds + buf * 8192;
    const char* cB = lds + 16384 + buf * 24576;
#pragma unroll
    for (int ks = 0; ks < 2; ++ks) {
      bf16x8 a[2], b[6];
#pragma unroll
      for (int mf = 0; mf < 2; ++mf) {
        int mloc = wm * 32 + mf * 16 + (lane & 15);
        int ka = (ks * 64 + (lane >> 4) * 16) ^ ((mloc & 7) << 4);
        a[mf] = *(const bf16x8*)(cA + mloc * 128 + ka);
      }
#pragma unroll
      for (int nf = 0; nf < 6; ++nf) {
        int nloc = wn * 96 + nf * 16 + (lane & 15);
        int kb = (ks * 64 + (lane >> 4) * 16) ^ ((nloc & 7) << 4);
        b[nf] = *(const bf16x8*)(cB + nloc * 128 + kb);
      }
#pragma unroll
      for (int mf = 0; mf < 2; ++mf)
#pragma unroll
        for (int nf = 0; nf < 6; ++nf)
          acc[mf][nf] = __builtin_amdgcn_mfma_f32_16x16x32_bf16(a[mf], b[nf], acc[mf][nf], 0, 0, 0);
    }
    if (kt < 3) writeA(buf ^ 1);
    __syncthreads();
  }
#pragma unroll
  for (int mf = 0; mf < 2; ++mf)
#pragma unroll
    for (int nf = 0; nf < 6; ++nf) {
      int n = wn * 96 + nf * 16 + (lane & 15);
      int jj = 0, rr = n;
#pragma unroll
      for (int s = 0; s < 3; ++s) {
        int w = (((g - jj) & 3) < 2) ? 64 : 32;
        if (rr >= w) { rr -= w; ++jj; }
      }
      int v = (g - jj) & 3;
      int offv = (v < 2) ? (v << 6) : (64 + (v << 5));
      int col = 512 + jj * 192 + offv + rr;
#pragma unroll
      for (int r = 0; r < 4; ++r) {
        int row = mb * 64 + wm * 32 + mf * 16 + (lane >> 4) * 4 + r;
        Abuf[fragIdxA(row, col)] = f2bf(acc[mf][nf][r]);
      }
    }
}

// ---------------- merged G1+G2 (one launch; independent block ranges)
__global__ __launch_bounds__(256) void g12(const float* __restrict__ x,
                                           const unsigned short* __restrict__ Wt,
                                           const float* __restrict__ h,
                                           const unsigned short* __restrict__ Bg,
                                           unsigned short* __restrict__ Abuf) {
  __shared__ char lds[65536];
  int b = blockIdx.x, tid = threadIdx.x;
  if (b < 512) {
    g1_body(x, Wt, Abuf, lds, b >> 1, b & 1, tid);
  } else {
    int b2 = b - 512;
    g2_body(h, Bg, Abuf, lds, b2 >> 2, b2 & 3, tid);
  }
}

// ---------------- G3: fused GEMM + GRU epilogue, 32x32x16, single barrier per kt
// grid (1024): xcd-interleaved remap (neutral-safe); BM=128, 64 cols of group j
// LDS: A 2x16KB @0, B 2x24KB @32768 (80 KiB)
__global__ __launch_bounds__(256) void g3_main(const unsigned short* __restrict__ Abuf,
                                               const unsigned short* __restrict__ Btp,
                                               const float* __restrict__ h,
                                               const float* __restrict__ bias_r,
                                               const float* __restrict__ bias_g,
                                               const float* __restrict__ bias_u,
                                               float* __restrict__ out) {
  __shared__ char lds[81920];
  const int tid = threadIdx.x, lane = tid & 63, wid = tid >> 6;
  const int flat = blockIdx.x;
  const int xcd = flat & 7, idx = flat >> 3;
  const int mb = xcd * 8 + (idx & 7);
  const int cj = idx >> 3;
  const int cb = cj & 3, j = cj >> 2;
  const int wm = wid >> 1, wn = wid & 1;
  f32x16 acc[2][4] = {};   // [mblk][plane]

  const char* AbufB = (const char*)Abuf;
  const char* BtpB  = (const char*)Btp;

  auto stage = [&](int kt, int buf) {
    int cc = (kt < 8) ? kt : (8 + j * 3 + (kt - 8));
    const char* asrc = AbufB + (size_t)(mb * 20 + cc) * 16384 + tid * 16;
    const char* bsrc = BtpB + (size_t)(((j * 11 + kt) * 4 + cb)) * 24576 + tid * 16;
#pragma unroll
    for (int it = 0; it < 4; ++it)
      gload16(asrc + it * 4096, lds + buf * 16384 + it * 4096 + wid * 1024);
#pragma unroll
    for (int it = 0; it < 6; ++it)
      gload16(bsrc + it * 4096, lds + 32768 + buf * 24576 + it * 4096 + wid * 1024);
  };

  stage(0, 0);
#pragma unroll
  for (int kt = 0; kt < 11; ++kt) {
    const int buf = kt & 1;
    // single barrier per kt: stage(kt)'s writes (to buf) must be complete,
    // then everyone crosses; stage(kt+1) after the barrier writes only buf^1.
    asm volatile("s_waitcnt vmcnt(0)" ::: "memory");
    __builtin_amdgcn_s_barrier();
    __builtin_amdgcn_sched_barrier(0);
    if (kt < 10) stage(kt + 1, buf ^ 1);
    __builtin_amdgcn_s_setprio(1);
    const char* aB = lds + buf * 16384 + wm * 8192 + lane * 16;
    const char* bB = lds + 32768 + buf * 24576 + wn * 4096 + lane * 16;
#pragma unroll
    for (int k4 = 0; k4 < 4; ++k4) {
      bf16x8 a0 = *(const bf16x8*)(aB + k4 * 1024);
      bf16x8 a1 = *(const bf16x8*)(aB + 4096 + k4 * 1024);
#pragma unroll
      for (int q = 0; q < 3; ++q) {
        const int p = (kt < 8) ? q : ((q == 2) ? 3 : q);
        bf16x8 b = *(const bf16x8*)(bB + q * 8192 + k4 * 1024);
        acc[0][p] = __builtin_amdgcn_mfma_f32_32x32x16_bf16(a0, b, acc[0][p], 0, 0, 0);
        acc[1][p] = __builtin_amdgcn_mfma_f32_32x32x16_bf16(a1, b, acc[1][p], 0, 0, 0);
      }
    }
    __builtin_amdgcn_s_setprio(0);
    __builtin_amdgcn_sched_barrier(0);
  }
  // fused GRU epilogue; 32x32 C/D: col = lane&31, row = (r&3) + 8*(r>>2) + 4*(lane>>5)
  int cg = j * 256 + cb * 64 + wn * 32 + (lane & 31);
  float br = bias_r[cg], bg = bias_g[cg], bu = bias_u[cg];
#pragma unroll
  for (int mblk = 0; mblk < 2; ++mblk)
#pragma unroll
    for (int r = 0; r < 16; ++r) {
      int row = mb * 128 + wm * 64 + mblk * 32 + (r & 3) + 8 * (r >> 2) + 4 * (lane >> 5);
      float p0 = acc[mblk][0][r], p1 = acc[mblk][1][r];
      float p2 = acc[mblk][2][r], p3 = acc[mblk][3][r];
      float rr = sigm(p0 + br);
      float zz = sigm(p1 + bg);
      float ct = tanha(p2 + rr * p3 + bu);
      float hv = h[(size_t)row * 1024 + cg];
      out[(size_t)row * 1024 + cg] = zz * hv + (1.0f - zz) * ct;
    }
}

extern "C" void kernel_launch(void* const* d_in, const int* in_sizes, int n_in,
                              void* d_out, int out_size, void* d_ws, size_t ws_size,
                              hipStream_t stream) {
  const float* x   = (const float*)d_in[0];
  const float* h   = (const float*)d_in[1];
  const float* W   = (const float*)d_in[2];
  const float* W1  = (const float*)d_in[3];
  const float* W2  = (const float*)d_in[4];
  const float* W3  = (const float*)d_in[5];
  const float* U   = (const float*)d_in[6];
  const float* U1  = (const float*)d_in[7];
  const float* U2  = (const float*)d_in[8];
  const float* U3  = (const float*)d_in[9];
  const float* UU   = (const float*)d_in[10];
  const float* UU1  = (const float*)d_in[11];
  const float* UU2  = (const float*)d_in[12];
  const float* UU3  = (const float*)d_in[13];
  const float* UUU   = (const float*)d_in[14];
  const float* UUU1  = (const float*)d_in[15];
  const float* UUU2  = (const float*)d_in[16];
  const float* UUU3  = (const float*)d_in[17];
  const float* UUUU   = (const float*)d_in[18];
  const float* UUUU1  = (const float*)d_in[19];
  const float* UUUU2  = (const float*)d_in[20];
  const float* UUUU3  = (const float*)d_in[21];
  const float* bias_r = (const float*)d_in[22];
  const float* bias_g = (const float*)d_in[23];
  const float* bias_u = (const float*)d_in[24];

  char* ws = (char*)d_ws;
  unsigned short* Abuf = (unsigned short*)(ws);              // 8192x1280 bf16, frag-ordered
  unsigned short* Wt   = (unsigned short*)(ws + 20971520);   // 256x1024 bf16
  unsigned short* Bg   = (unsigned short*)(ws + 21495808);   // 4x192x256 bf16
  unsigned short* Btp  = (unsigned short*)(ws + 21889024);   // 176x24 frag-ordered bf16
  float* out = (float*)d_out;

  s123<<<10240, 256, 0, stream>>>(W, U, UU, UUU, UUUU,
                                  W1, W2, W3, U1, U2, U3, UU1, UU2, UU3,
                                  UUU1, UUU2, UUU3, UUUU1, UUUU2, UUUU3,
                                  Wt, Bg, Btp);
  g12<<<1024, 256, 0, stream>>>(x, Wt, h, Bg, Abuf);
  g3_main<<<1024, 256, 0, stream>>>(Abuf, Btp, h, bias_r, bias_g, bias_u, out);
}

// Round 13
// 90.465 us; speedup vs baseline: 1.1013x; 1.0390x over previous
//
#include <hip/hip_runtime.h>

typedef short bf16x8 __attribute__((ext_vector_type(8)));
typedef float f32x4 __attribute__((ext_vector_type(4)));
typedef float f32x16 __attribute__((ext_vector_type(16)));

__device__ __forceinline__ unsigned short f2bf(float f) {
  union { float f; unsigned u; } c; c.f = f;
  unsigned u = c.u;
  u += 0x7FFFu + ((u >> 16) & 1u);   // RNE
  return (unsigned short)(u >> 16);
}
__device__ __forceinline__ float bf2f(unsigned short h) {
  union { unsigned u; float f; } c; c.u = ((unsigned)h) << 16;
  return c.f;
}
// truncation split: hi = trunc-to-bf16(v), lo = RNE(v - hi)
__device__ __forceinline__ void split2(float v, unsigned short& hi, unsigned short& lo) {
  union { float f; unsigned u; } c; c.f = v;
  unsigned uh = c.u & 0xFFFF0000u;
  hi = (unsigned short)(uh >> 16);
  union { unsigned u; float f; } d; d.u = uh;
  lo = f2bf(v - d.f);
}
__device__ __forceinline__ void gload16(const void* g, void* l) {
  __builtin_amdgcn_global_load_lds((const __attribute__((address_space(1))) void*)g,
                                   (__attribute__((address_space(3))) void*)l, 16, 0, 0);
}
__device__ __forceinline__ float sigm(float x) { return 1.0f / (1.0f + __expf(-x)); }
__device__ __forceinline__ float tanha(float x) { return 1.0f - 2.0f / (1.0f + __expf(2.0f * x)); }

// Abuf 32x32x16-fragment layout (ushort index) for (row 0..8191, col 0..1279):
// 1 KiB frag = (mb, cc, rowblk, k4); within: lane = hi*32 + (row&31), e = col&7
__device__ __forceinline__ size_t fragIdxA(int row, int col) {
  int mb = row >> 7, rb = (row >> 5) & 3, l5 = row & 31;
  int cc = col >> 6, k4 = (col >> 4) & 3, hi = (col >> 3) & 1, e = col & 7;
  return ((size_t)(mb * 20 + cc) * 16 + rb * 4 + k4) * 512 + (hi * 32 + l5) * 8 + e;
}

// ---------------- merged setup kernel ----------------
// [0, 262144): Wt[n][k] = W[k][n]                    (256x1024 bf16)
// [262144, 458752): Bg[g][n][k]                      (4x192x256 bf16)
// [458752, 1835008): Btp frag-ordered, 7 kt-slots    (112 blocks x 24 frags x 512)
//   kt-slot kts in [0,7): kt = kts<4 ? kts : kts+4   (kt 4..7 dropped: identical to 0..3)
__global__ __launch_bounds__(256) void s123(
    const float* __restrict__ W,
    const float* __restrict__ U, const float* __restrict__ UU,
    const float* __restrict__ UUU, const float* __restrict__ UUUU,
    const float* __restrict__ W1, const float* __restrict__ W2, const float* __restrict__ W3,
    const float* __restrict__ A1, const float* __restrict__ A2, const float* __restrict__ A3,
    const float* __restrict__ B1, const float* __restrict__ B2, const float* __restrict__ B3,
    const float* __restrict__ C1, const float* __restrict__ C2, const float* __restrict__ C3,
    const float* __restrict__ D1, const float* __restrict__ D2, const float* __restrict__ D3,
    unsigned short* __restrict__ Wt, unsigned short* __restrict__ Bg,
    unsigned short* __restrict__ Btp) {
  int gidx = blockIdx.x * 256 + threadIdx.x;
  if (gidx < 262144) {
    int idx = gidx;
    int n = idx >> 10, k = idx & 1023;
    Wt[idx] = f2bf(W[k * 256 + n]);
  } else if (gidx < 458752) {
    int idx = gidx - 262144;
    int g = idx / 49152;
    int rem = idx - g * 49152;
    int n = rem >> 8, k = rem & 255;
    int jj = 0, rr = n;
#pragma unroll
    for (int s = 0; s < 3; ++s) {
      int w = (((g - jj) & 3) < 2) ? 64 : 32;
      if (rr >= w) { rr -= w; ++jj; }
    }
    int v = (g - jj) & 3;
    int rv = (v < 2) ? 64 : 32;
    const float* M = (v == 0) ? U : (v == 1) ? UU : (v == 2) ? UUU : UUUU;
    Bg[idx] = f2bf(M[(jj * 256 + k) * rv + rr]);
  } else {
    int idx = gidx - 458752;                 // linear ushort index into frag-ordered Btp
    int blk = idx / 12288;                   // (j*7 + kts)*4 + cb
    int w   = idx - blk * 12288;
    int frag = w >> 9, fl = (w >> 3) & 63, e = w & 7;
    int cb = blk & 3, jk = blk >> 2;
    int kts = jk % 7, j = jk / 7;
    int kt = (kts < 4) ? kts : (kts + 4);
    int q = frag >> 3, colblk = (frag >> 2) & 1, k4 = frag & 3;
    int c  = cb * 64 + colblk * 32 + (fl & 31);
    int k2 = k4 * 16 + (fl >> 5) * 8 + e;
    float val;
    if (kt < 8) {
      int kk = kt * 64 + k2;                 // kt in 0..3 here, no wrap needed
      const float* Wp = (q == 0) ? W1 : (q == 1) ? W2 : W3;
      val = Wp[kk * 1024 + j * 256 + c];
    } else {
      int kT = (kt - 8) * 64 + k2;
      int v, r, rv;
      if (kT < 64)       { v = 0; r = kT;       rv = 64; }
      else if (kT < 128) { v = 1; r = kT - 64;  rv = 64; }
      else if (kT < 160) { v = 2; r = kT - 128; rv = 32; }
      else               { v = 3; r = kT - 160; rv = 32; }
      const float* M;
      if (v == 0)      M = (q == 0) ? A1 : (q == 1) ? A2 : A3;
      else if (v == 1) M = (q == 0) ? B1 : (q == 1) ? B2 : B3;
      else if (v == 2) M = (q == 0) ? C1 : (q == 1) ? C2 : C3;
      else             M = (q == 0) ? D1 : (q == 1) ? D2 : D3;
      val = M[(j * rv + r) * 256 + c];
    }
    Btp[idx] = f2bf(val);
  }
}

// ---------------- G1 body: xw = x @ W, hi/lo 2-pass, BM=32 BN=128
__device__ __forceinline__ void g1_body(const float* __restrict__ x,
                                        const unsigned short* __restrict__ Wt,
                                        unsigned short* __restrict__ Abuf,
                                        char* lds, int mb, int nb, int tid) {
  const int lane = tid & 63, wid = tid >> 6;
  const int wn = wid;
  f32x4 acc[2][2] = {};
  float4 xr[2];
  const int r0 = tid >> 4, f4c = tid & 15;
  const float* xbase = x + (size_t)(mb * 32) * 1024 + f4c * 4;

  auto loadX = [&](int kt) {
#pragma unroll
    for (int q = 0; q < 2; ++q)
      xr[q] = *(const float4*)(xbase + (size_t)(q * 16 + r0) * 1024 + kt * 64);
  };
  auto writeA = [&](int buf) {
#pragma unroll
    for (int q = 0; q < 2; ++q) {
      int row = q * 16 + r0;
      float4 v = xr[q];
      unsigned short h0, h1, h2, h3, l0, l1, l2, l3;
      split2(v.x, h0, l0); split2(v.y, h1, l1);
      split2(v.z, h2, l2); split2(v.w, h3, l3);
      int ba = row * 128 + ((f4c * 8) ^ ((row & 7) << 4));
      *(uint2*)(lds + buf * 4096 + ba) =
          make_uint2(((unsigned)h1 << 16) | h0, ((unsigned)h3 << 16) | h2);
      *(uint2*)(lds + 8192 + buf * 4096 + ba) =
          make_uint2(((unsigned)l1 << 16) | l0, ((unsigned)l3 << 16) | l2);
    }
  };
  auto stageB = [&](int kt, int buf) {
#pragma unroll
    for (int it = 0; it < 4; ++it) {
      int nloc = it * 32 + wid * 8 + (lane >> 3);
      const char* src = (const char*)Wt + (size_t)(nb * 128 + nloc) * 2048 + kt * 128
                        + (((lane & 7) * 16) ^ ((nloc & 7) << 4));
      gload16(src, lds + 16384 + buf * 16384 + (it * 32 + wid * 8) * 128);
    }
  };

  loadX(0); stageB(0, 0); writeA(0);
  __syncthreads();
#pragma unroll 2
  for (int kt = 0; kt < 16; ++kt) {
    int buf = kt & 1;
    if (kt < 15) {
      loadX(kt + 1); stageB(kt + 1, buf ^ 1);
      asm volatile("s_waitcnt vmcnt(6)" ::: "memory");
    } else {
      asm volatile("s_waitcnt vmcnt(0)" ::: "memory");
    }
    __builtin_amdgcn_s_barrier();
    __builtin_amdgcn_sched_barrier(0);
    const char* hA = lds + buf * 4096;
    const char* lA = lds + 8192 + buf * 4096;
    const char* bB = lds + 16384 + buf * 16384;
#pragma unroll
    for (int ks = 0; ks < 2; ++ks) {
      bf16x8 ah[2], al[2], b[2];
#pragma unroll
      for (int mf = 0; mf < 2; ++mf) {
        int mloc = mf * 16 + (lane & 15);
        int ka = (ks * 64 + (lane >> 4) * 16) ^ ((mloc & 7) << 4);
        ah[mf] = *(const bf16x8*)(hA + mloc * 128 + ka);
        al[mf] = *(const bf16x8*)(lA + mloc * 128 + ka);
      }
#pragma unroll
      for (int nf = 0; nf < 2; ++nf) {
        int nloc = wn * 32 + nf * 16 + (lane & 15);
        int kb = (ks * 64 + (lane >> 4) * 16) ^ ((nloc & 7) << 4);
        b[nf] = *(const bf16x8*)(bB + nloc * 128 + kb);
      }
#pragma unroll
      for (int mf = 0; mf < 2; ++mf)
#pragma unroll
        for (int nf = 0; nf < 2; ++nf) {
          acc[mf][nf] = __builtin_amdgcn_mfma_f32_16x16x32_bf16(ah[mf], b[nf], acc[mf][nf], 0, 0, 0);
          acc[mf][nf] = __builtin_amdgcn_mfma_f32_16x16x32_bf16(al[mf], b[nf], acc[mf][nf], 0, 0, 0);
        }
    }
    if (kt < 15) writeA(buf ^ 1);
    __builtin_amdgcn_sched_barrier(0);
    asm volatile("s_waitcnt lgkmcnt(0)" ::: "memory");
    __builtin_amdgcn_s_barrier();
  }
#pragma unroll
  for (int mf = 0; mf < 2; ++mf)
#pragma unroll
    for (int nf = 0; nf < 2; ++nf)
#pragma unroll
      for (int r = 0; r < 4; ++r) {
        int row = mb * 32 + mf * 16 + (lane >> 4) * 4 + r;
        int col = nb * 128 + wn * 32 + nf * 16 + (lane & 15);
        float val = acc[mf][nf][r];
        unsigned short hi, lo;
        split2(val, hi, lo);
        Abuf[fragIdxA(row, col)] = hi;
        Abuf[fragIdxA(row, col + 256)] = lo;
      }
}

// ---------------- G2 body: zero-skip T = h_g @ Bg, BM=64, N=192, K=256
__device__ __forceinline__ void g2_body(const float* __restrict__ h,
                                        const unsigned short* __restrict__ Bg,
                                        unsigned short* __restrict__ Abuf,
                                        char* lds, int mb, int g, int tid) {
  const int lane = tid & 63, wid = tid >> 6;
  const int wm = wid >> 1, wn = wid & 1;
  f32x4 acc[2][6] = {};
  float4 hr[4];
  const int r0 = tid >> 4, f4c = tid & 15;
  const float* hbase = h + (size_t)(mb * 64) * 1024 + g * 256 + f4c * 4;

  auto loadH = [&](int kt) {
#pragma unroll
    for (int q = 0; q < 4; ++q)
      hr[q] = *(const float4*)(hbase + (size_t)(q * 16 + r0) * 1024 + kt * 64);
  };
  auto writeA = [&](int buf) {
#pragma unroll
    for (int q = 0; q < 4; ++q) {
      int row = q * 16 + r0;
      float4 v = hr[q];
      int ba = row * 128 + ((f4c * 8) ^ ((row & 7) << 4));
      *(uint2*)(lds + buf * 8192 + ba) =
          make_uint2(((unsigned)f2bf(v.y) << 16) | f2bf(v.x),
                     ((unsigned)f2bf(v.w) << 16) | f2bf(v.z));
    }
  };
  auto stageB = [&](int kt, int buf) {
#pragma unroll
    for (int it = 0; it < 6; ++it) {
      int nloc = it * 32 + wid * 8 + (lane >> 3);
      const char* src = (const char*)Bg + (size_t)(g * 192 + nloc) * 512 + kt * 128
                        + (((lane & 7) * 16) ^ ((nloc & 7) << 4));
      gload16(src, lds + 16384 + buf * 24576 + (it * 32 + wid * 8) * 128);
    }
  };

  loadH(0); stageB(0, 0); writeA(0);
  __syncthreads();
#pragma unroll
  for (int kt = 0; kt < 4; ++kt) {
    int buf = kt & 1;
    if (kt < 3) { loadH(kt + 1); stageB(kt + 1, buf ^ 1); }
    const char* cA = lds + buf * 8192;
    const char* cB = lds + 16384 + buf * 24576;
#pragma unroll
    for (int ks = 0; ks < 2; ++ks) {
      bf16x8 a[2], b[6];
#pragma unroll
      for (int mf = 0; mf < 2; ++mf) {
        int mloc = wm * 32 + mf * 16 + (lane & 15);
        int ka = (ks * 64 + (lane >> 4) * 16) ^ ((mloc & 7) << 4);
        a[mf] = *(const bf16x8*)(cA + mloc * 128 + ka);
      }
#pragma unroll
      for (int nf = 0; nf < 6; ++nf) {
        int nloc = wn * 96 + nf * 16 + (lane & 15);
        int kb = (ks * 64 + (lane >> 4) * 16) ^ ((nloc & 7) << 4);
        b[nf] = *(const bf16x8*)(cB + nloc * 128 + kb);
      }
#pragma unroll
      for (int mf = 0; mf < 2; ++mf)
#pragma unroll
        for (int nf = 0; nf < 6; ++nf)
          acc[mf][nf] = __builtin_amdgcn_mfma_f32_16x16x32_bf16(a[mf], b[nf], acc[mf][nf], 0, 0, 0);
    }
    if (kt < 3) writeA(buf ^ 1);
    __syncthreads();
  }
#pragma unroll
  for (int mf = 0; mf < 2; ++mf)
#pragma unroll
    for (int nf = 0; nf < 6; ++nf) {
      int n = wn * 96 + nf * 16 + (lane & 15);
      int jj = 0, rr = n;
#pragma unroll
      for (int s = 0; s < 3; ++s) {
        int w = (((g - jj) & 3) < 2) ? 64 : 32;
        if (rr >= w) { rr -= w; ++jj; }
      }
      int v = (g - jj) & 3;
      int offv = (v < 2) ? (v << 6) : (64 + (v << 5));
      int col = 512 + jj * 192 + offv + rr;
#pragma unroll
      for (int r = 0; r < 4; ++r) {
        int row = mb * 64 + wm * 32 + mf * 16 + (lane >> 4) * 4 + r;
        Abuf[fragIdxA(row, col)] = f2bf(acc[mf][nf][r]);
      }
    }
}

// ---------------- merged G1+G2 (one launch; independent block ranges)
__global__ __launch_bounds__(256) void g12(const float* __restrict__ x,
                                           const unsigned short* __restrict__ Wt,
                                           const float* __restrict__ h,
                                           const unsigned short* __restrict__ Bg,
                                           unsigned short* __restrict__ Abuf) {
  __shared__ char lds[65536];
  int b = blockIdx.x, tid = threadIdx.x;
  if (b < 512) {
    g1_body(x, Wt, Abuf, lds, b >> 1, b & 1, tid);
  } else {
    int b2 = b - 512;
    g2_body(h, Bg, Abuf, lds, b2 >> 2, b2 & 3, tid);
  }
}

// ---------------- G3: fused GEMM + GRU epilogue, 32x32x16, B-pair-shared schedule
// 11 steps: h0,l0,h1,l1,h2,l2,h3,l3,t0,t1,t2. lo-steps stage A only and reuse
// the hi-step's B tile (identical W1/W2/W3 rows). Two barriers/step, counted vmcnt.
// LDS: A 2x16KB @0, B 2x24KB @32768 (80 KiB)
__global__ __launch_bounds__(256) void g3_main(const unsigned short* __restrict__ Abuf,
                                               const unsigned short* __restrict__ Btp,
                                               const float* __restrict__ h,
                                               const float* __restrict__ bias_r,
                                               const float* __restrict__ bias_g,
                                               const float* __restrict__ bias_u,
                                               float* __restrict__ out) {
  __shared__ char lds[81920];
  const int tid = threadIdx.x, lane = tid & 63, wid = tid >> 6;
  const int flat = blockIdx.x;
  const int xcd = flat & 7, idx = flat >> 3;
  const int mb = xcd * 8 + (idx & 7);
  const int cj = idx >> 3;
  const int cb = cj & 3, j = cj >> 2;
  const int wm = wid >> 1, wn = wid & 1;
  f32x16 acc[2][4] = {};   // [mblk][plane]

  const char* AbufB = (const char*)Abuf;
  const char* BtpB  = (const char*)Btp;

  // step metadata (index by unrolled-constant step -> fully folded)
  const int A_cc[11]  = {0, 4, 1, 5, 2, 6, 3, 7, 8 + j * 3, 9 + j * 3, 10 + j * 3};
  const int B_kts[11] = {0, 0, 1, 1, 2, 2, 3, 3, 4, 5, 6};
  const bool B_st[11] = {true, false, true, false, true, false, true, false, true, true, true};
  const int B_buf[11] = {0, 0, 1, 1, 0, 0, 1, 1, 0, 1, 0};

  auto stageA = [&](int step, int buf) {
    const char* asrc = AbufB + (size_t)(mb * 20 + A_cc[step]) * 16384 + tid * 16;
#pragma unroll
    for (int it = 0; it < 4; ++it)
      gload16(asrc + it * 4096, lds + buf * 16384 + it * 4096 + wid * 1024);
  };
  auto stageBt = [&](int step, int buf) {
    const char* bsrc = BtpB + (size_t)((j * 7 + B_kts[step]) * 4 + cb) * 24576 + tid * 16;
#pragma unroll
    for (int it = 0; it < 6; ++it)
      gload16(bsrc + it * 4096, lds + 32768 + buf * 24576 + it * 4096 + wid * 1024);
  };

  stageA(0, 0); stageBt(0, 0);
#pragma unroll
  for (int i = 0; i < 11; ++i) {
    const int abuf = i & 1, bbuf = B_buf[i];
    if (i < 10) {
      stageA(i + 1, (i + 1) & 1);
      if (B_st[i + 1]) {
        stageBt(i + 1, B_buf[i + 1]);
        asm volatile("s_waitcnt vmcnt(10)" ::: "memory");
      } else {
        asm volatile("s_waitcnt vmcnt(4)" ::: "memory");
      }
    } else {
      asm volatile("s_waitcnt vmcnt(0)" ::: "memory");
    }
    __builtin_amdgcn_s_barrier();
    __builtin_amdgcn_sched_barrier(0);
    __builtin_amdgcn_s_setprio(1);
    const char* aB = lds + abuf * 16384 + wm * 8192 + lane * 16;
    const char* bB = lds + 32768 + bbuf * 24576 + wn * 4096 + lane * 16;
#pragma unroll
    for (int k4 = 0; k4 < 4; ++k4) {
      bf16x8 a0 = *(const bf16x8*)(aB + k4 * 1024);
      bf16x8 a1 = *(const bf16x8*)(aB + 4096 + k4 * 1024);
#pragma unroll
      for (int q = 0; q < 3; ++q) {
        const int p = (i < 8) ? q : ((q == 2) ? 3 : q);
        bf16x8 b = *(const bf16x8*)(bB + q * 8192 + k4 * 1024);
        acc[0][p] = __builtin_amdgcn_mfma_f32_32x32x16_bf16(a0, b, acc[0][p], 0, 0, 0);
        acc[1][p] = __builtin_amdgcn_mfma_f32_32x32x16_bf16(a1, b, acc[1][p], 0, 0, 0);
      }
    }
    __builtin_amdgcn_s_setprio(0);
    __builtin_amdgcn_sched_barrier(0);
    __builtin_amdgcn_s_barrier();
  }
  // fused GRU epilogue; 32x32 C/D: col = lane&31, row = (r&3) + 8*(r>>2) + 4*(lane>>5)
  int cg = j * 256 + cb * 64 + wn * 32 + (lane & 31);
  float br = bias_r[cg], bg = bias_g[cg], bu = bias_u[cg];
#pragma unroll
  for (int mblk = 0; mblk < 2; ++mblk)
#pragma unroll
    for (int r = 0; r < 16; ++r) {
      int row = mb * 128 + wm * 64 + mblk * 32 + (r & 3) + 8 * (r >> 2) + 4 * (lane >> 5);
      float p0 = acc[mblk][0][r], p1 = acc[mblk][1][r];
      float p2 = acc[mblk][2][r], p3 = acc[mblk][3][r];
      float rr = sigm(p0 + br);
      float zz = sigm(p1 + bg);
      float ct = tanha(p2 + rr * p3 + bu);
      float hv = h[(size_t)row * 1024 + cg];
      out[(size_t)row * 1024 + cg] = zz * hv + (1.0f - zz) * ct;
    }
}

extern "C" void kernel_launch(void* const* d_in, const int* in_sizes, int n_in,
                              void* d_out, int out_size, void* d_ws, size_t ws_size,
                              hipStream_t stream) {
  const float* x   = (const float*)d_in[0];
  const float* h   = (const float*)d_in[1];
  const float* W   = (const float*)d_in[2];
  const float* W1  = (const float*)d_in[3];
  const float* W2  = (const float*)d_in[4];
  const float* W3  = (const float*)d_in[5];
  const float* U   = (const float*)d_in[6];
  const float* U1  = (const float*)d_in[7];
  const float* U2  = (const float*)d_in[8];
  const float* U3  = (const float*)d_in[9];
  const float* UU   = (const float*)d_in[10];
  const float* UU1  = (const float*)d_in[11];
  const float* UU2  = (const float*)d_in[12];
  const float* UU3  = (const float*)d_in[13];
  const float* UUU   = (const float*)d_in[14];
  const float* UUU1  = (const float*)d_in[15];
  const float* UUU2  = (const float*)d_in[16];
  const float* UUU3  = (const float*)d_in[17];
  const float* UUUU   = (const float*)d_in[18];
  const float* UUUU1  = (const float*)d_in[19];
  const float* UUUU2  = (const float*)d_in[20];
  const float* UUUU3  = (const float*)d_in[21];
  const float* bias_r = (const float*)d_in[22];
  const float* bias_g = (const float*)d_in[23];
  const float* bias_u = (const float*)d_in[24];

  char* ws = (char*)d_ws;
  unsigned short* Abuf = (unsigned short*)(ws);              // 8192x1280 bf16, frag-ordered
  unsigned short* Wt   = (unsigned short*)(ws + 20971520);   // 256x1024 bf16
  unsigned short* Bg   = (unsigned short*)(ws + 21495808);   // 4x192x256 bf16
  unsigned short* Btp  = (unsigned short*)(ws + 21889024);   // 112x24 frag-ordered bf16
  float* out = (float*)d_out;

  s123<<<7168, 256, 0, stream>>>(W, U, UU, UUU, UUUU,
                                 W1, W2, W3, U1, U2, U3, UU1, UU2, UU3,
                                 UUU1, UUU2, UUU3, UUUU1, UUUU2, UUUU3,
                                 Wt, Bg, Btp);
  g12<<<1024, 256, 0, stream>>>(x, Wt, h, Bg, Abuf);
  g3_main<<<1024, 256, 0, stream>>>(Abuf, Btp, h, bias_r, bias_g, bias_u, out);
}